// Round 2
// baseline (257.570 us; speedup 1.0000x reference)
//
#include <hip/hip_runtime.h>
#include <hip/hip_bf16.h>
#include <math.h>

// ---------------- workspace layout (float indices) ----------------
#define WS_S    0      // s[b*3+c]            : 48
#define WS_G    64     // G[(b*3+c)*4+e]      : 192
#define WS_N    256    // N[(b*3+c)*4+e]      : 192
#define WS_GATE 448    // gates[b*4+e]        : 64
// memset first 2048 bytes each launch

typedef float  float4v  __attribute__((ext_vector_type(4)));
typedef short  short8v  __attribute__((ext_vector_type(8)));
typedef _Float16 half2v __attribute__((ext_vector_type(2)));

__device__ __forceinline__ short bf16b(float f) {
    unsigned u = __builtin_bit_cast(unsigned, f);
    u = (u + 0x7FFFu + ((u >> 16) & 1u)) >> 16;   // RNE
    return (short)u;
}

__device__ __forceinline__ float dot2f(unsigned h, unsigned w, float acc) {
#if __has_builtin(__builtin_amdgcn_fdot2)
    union { unsigned u; half2v h; } a, b; a.u = h; b.u = w;
    return __builtin_amdgcn_fdot2(a.h, b.h, acc, false);
#else
    union { unsigned u; _Float16 v[2]; } a, b; a.u = h; b.u = w;
    return acc + (float)a.v[0]*(float)b.v[0] + (float)a.v[1]*(float)b.v[1];
#endif
}

// ---------------- kernel A: s[b,c] = sum(ref[b,c,:,:]) ----------------
__global__ void k_refsum(const float* __restrict__ ref, float* __restrict__ ws) {
    int bc = blockIdx.x, chunk = blockIdx.y, t = threadIdx.x;
    const float4* p4 = (const float4*)(ref + (size_t)bc*65536 + (size_t)chunk*8192);
    float acc = 0.f;
    #pragma unroll
    for (int i = 0; i < 8; ++i) { float4 v = p4[i*256 + t]; acc += v.x + v.y + v.z + v.w; }
    #pragma unroll
    for (int off = 32; off > 0; off >>= 1) acc += __shfl_down(acc, off);
    __shared__ float red[4];
    if ((t & 63) == 0) red[t >> 6] = acc;
    __syncthreads();
    if (t == 0) atomicAdd(&ws[WS_S + bc], red[0] + red[1] + red[2] + red[3]);
}

// -------- kernel B: G[b,c,e] = sum_hw x*w_gate ; N likewise --------
__global__ void k_gatedots(const float* __restrict__ x, const float* __restrict__ wg,
                           const float* __restrict__ wn, float* __restrict__ ws) {
    int bc = blockIdx.x;                 // b*3+c
    int c  = bc % 3;
    int chunk = blockIdx.y, t = threadIdx.x;
    const float4* x4  = (const float4*)(x + (size_t)bc*65536 + (size_t)chunk*4096);
    const float4* wg4 = (const float4*)(wg + ((size_t)c*65536 + (size_t)chunk*4096)*4);
    const float4* wn4 = (const float4*)(wn + ((size_t)c*65536 + (size_t)chunk*4096)*4);
    float aG[4] = {0,0,0,0}, aN[4] = {0,0,0,0};
    #pragma unroll
    for (int i = 0; i < 4; ++i) {
        float4 xv = x4[i*256 + t];
        int row = (i*256 + t) * 4;
        float xs[4] = {xv.x, xv.y, xv.z, xv.w};
        #pragma unroll
        for (int l = 0; l < 4; ++l) {
            float4 g = wg4[row + l], n = wn4[row + l];
            aG[0] += xs[l]*g.x; aG[1] += xs[l]*g.y; aG[2] += xs[l]*g.z; aG[3] += xs[l]*g.w;
            aN[0] += xs[l]*n.x; aN[1] += xs[l]*n.y; aN[2] += xs[l]*n.z; aN[3] += xs[l]*n.w;
        }
    }
    #pragma unroll
    for (int off = 32; off > 0; off >>= 1) {
        #pragma unroll
        for (int e = 0; e < 4; ++e) { aG[e] += __shfl_down(aG[e], off); aN[e] += __shfl_down(aN[e], off); }
    }
    __shared__ float red[4][8];
    if ((t & 63) == 0) {
        #pragma unroll
        for (int e = 0; e < 4; ++e) { red[t>>6][e] = aG[e]; red[t>>6][4+e] = aN[e]; }
    }
    __syncthreads();
    if (t < 8) {
        float s = red[0][t] + red[1][t] + red[2][t] + red[3][t];
        if (t < 4) atomicAdd(&ws[WS_G + bc*4 + t],     s);
        else       atomicAdd(&ws[WS_N + bc*4 + (t-4)], s);
    }
}

// -------- kernel C: prompt, logits, top-k, gates, loss (tiny) --------
__global__ void k_gating(const float* __restrict__ noise,
                         const float* __restrict__ mw1, const float* __restrict__ mb1,
                         const float* __restrict__ mw2, const float* __restrict__ mb2,
                         const float* __restrict__ enw, const float* __restrict__ enb,
                         const float* __restrict__ fp,
                         float* __restrict__ ws, float* __restrict__ out) {
    __shared__ float gL[16][4], pL[16][4], cvs[2];
    int t = threadIdx.x;
    if (t < 16) {
        int b = t;
        float sc[3];
        for (int c = 0; c < 3; ++c) sc[c] = ws[WS_S + b*3 + c] * (1.f/256.f);
        float pooled[12];
        for (int i = 0; i < 12; ++i) { int r = i % 6; pooled[i] = (r < 3) ? sc[r] : 0.f; }
        float m1[6];
        for (int o = 0; o < 6; ++o) {
            float a = mb1[o];
            for (int i = 0; i < 12; ++i) a += mw1[o*12 + i] * pooled[i];
            m1[o] = fmaxf(a, 0.f);
        }
        float m2[6];
        for (int o = 0; o < 6; ++o) {
            float a = mb2[o];
            for (int i = 0; i < 6; ++i) a += mw2[o*6 + i] * m1[i];
            m2[o] = a * fp[(size_t)o * 33024];   // * fre_prompt[o,0,0]
        }
        float dc[3];
        for (int o = 0; o < 3; ++o) {            // only real-part channels matter
            float a = enb[o];
            for (int i = 0; i < 6; ++i) a += enw[o*6 + i] * m2[i];
            dc[o] = fmaxf(a, 0.f) * (1.f/256.f); // mean of irfft2 = Re(DC)/256
        }
        float mx = fmaxf(dc[0], fmaxf(dc[1], dc[2]));
        float e0 = expf(dc[0]-mx), e1 = expf(dc[1]-mx), e2 = expf(dc[2]-mx);
        float inv = 1.f / (e0 + e1 + e2);
        float pc[3] = { e0*inv + 1.f, e1*inv + 1.f, e2*inv + 1.f };
        float cl[4], sg[4], nz[4];
        for (int e = 0; e < 4; ++e) {
            float a = 0.f, nr = 0.f;
            for (int c = 0; c < 3; ++c) {
                a  += pc[c] * ws[WS_G + (b*3 + c)*4 + e];
                nr += pc[c] * ws[WS_N + (b*3 + c)*4 + e];
            }
            cl[e] = a;
            float sp = (nr > 20.f) ? nr : log1pf(expf(nr));
            sg[e] = sp + 0.01f;
            nz[e] = a + noise[b*4 + e] * sg[e];
        }
        int i0 = 0; float v0 = nz[0];
        for (int e = 1; e < 4; ++e) if (nz[e] > v0) { v0 = nz[e]; i0 = e; }
        int i1 = -1; float v1 = -3.4e38f;
        for (int e = 0; e < 4; ++e) if (e != i0 && nz[e] > v1) { v1 = nz[e]; i1 = e; }
        float v2 = -3.4e38f;
        for (int e = 0; e < 4; ++e) if (e != i0 && e != i1 && nz[e] > v2) v2 = nz[e];
        float ex = expf(v1 - v0), den = 1.f + ex;
        float gate[4] = {0.f, 0.f, 0.f, 0.f};
        gate[i0] = 1.f/den; gate[i1] = ex/den;
        for (int e = 0; e < 4; ++e) {
            ws[WS_GATE + b*4 + e] = gate[e];
            gL[b][e] = gate[e];
            float thr = (nz[e] > v2) ? v2 : v1;   // thr_in = 3rd-largest, thr_out = 2nd
            pL[b][e] = 0.5f * (1.f + erff((cl[e] - thr) / sg[e] * 0.70710678118f));
        }
    }
    __syncthreads();
    if (t < 2) {
        float v[4];
        for (int e = 0; e < 4; ++e) {
            float s = 0.f;
            for (int b = 0; b < 16; ++b) s += (t == 0) ? gL[b][e] : pL[b][e];
            v[e] = s;
        }
        float mean = 0.25f * (v[0] + v[1] + v[2] + v[3]);
        float var = 0.f;
        for (int e = 0; e < 4; ++e) { float d = v[e] - mean; var += d*d; }
        var *= (1.f/3.f);
        cvs[t] = var / (mean*mean + 1e-10f);
    }
    __syncthreads();
    if (t == 0) out[1048576] = (cvs[0] + cvs[1]) * 0.01f;
}

// -------- kernel D: fused expert convs, MFMA conv1 + dot2 conv2 --------
// block = 256 thr, one 16x16 output tile of one batch elem; loops over
// the (exactly 2) active experts. LDS ~47.5 KB -> 3 blocks/CU.
__global__ __launch_bounds__(256, 2)
void k_experts(const float* __restrict__ x,  const float* __restrict__ ew1,
               const float* __restrict__ eb1, const float* __restrict__ ew2,
               const float* __restrict__ eb2, const float* __restrict__ ws,
               float* __restrict__ out) {
    __shared__ float in_s[1200];                       // [3][20][20] f32
    __shared__ int   lut[32];                          // k -> in_s offset
    __shared__ __align__(16) uint2 hid[8*324*2];       // [c8][324 px][2 halves] f16x4
    __shared__ __align__(16) unsigned w2s[288];        // [c8][tap][4] f16x2 pairs

    int t = threadIdx.x;
    int b = blockIdx.x >> 8, tile = blockIdx.x & 255;
    int ty0 = (tile >> 4) * 16, tx0 = (tile & 15) * 16;

    const float* xb = x + (size_t)b * 196608;
    for (int i = t; i < 1200; i += 256) {
        int ci = i / 400, r = i - ci*400, iy = r / 20, ix = r - iy*20;
        int gy = ty0 - 2 + iy, gx = tx0 - 2 + ix;
        float v = 0.f;
        if (gy >= 0 && gy < 256 && gx >= 0 && gx < 256) v = xb[ci*65536 + gy*256 + gx];
        in_s[i] = v;
    }
    if (t < 32) {
        int k = t, off = 0;
        if (k < 27) { int ci = k/9, r = k - ci*9, kh = r/3, kw = r - kh*3; off = ci*400 + kh*20 + kw; }
        lut[k] = off;
    }
    __syncthreads();

    int lane = t & 63, wv = t >> 6;
    int qq = lane >> 4, mm = lane & 15;
    int m0 = wv * 16;
    int offj[8];
    #pragma unroll
    for (int j = 0; j < 8; ++j) offj[j] = lut[qq*8 + j];

    int oy = t >> 4, ox = t & 15;
    float accY = 0.f;

    for (int e = 0; e < 4; ++e) {
        float g = ws[WS_GATE + b*4 + e];
        if (g == 0.f) continue;                 // block-uniform
        __syncthreads();                        // prev phase C done

        // pack conv2 weights f16x2 (288 entries, 256 threads -> strided loop)
        for (int i = t; i < 288; i += 256) {
            int j = i & 3, rr = i >> 2, tap = rr % 9, c8 = rr / 9;
            const float* w2 = ew2 + e*576;
            int c0 = c8*8 + j*2;
            union { _Float16 h[2]; unsigned u; } pk;
            pk.h[0] = (_Float16)w2[c0*9 + tap];
            pk.h[1] = (_Float16)w2[(c0+1)*9 + tap];
            w2s[(c8*9 + tap)*4 + j] = pk.u;
        }

        // A-fragment: W[ch][k], ch = m0+mm, k = qq*8+j (zero-pad k>=27)
        short8v af;
        const float* w1 = ew1 + e*1728 + (m0 + mm)*27;
        #pragma unroll
        for (int j = 0; j < 8; ++j) {
            int k = qq*8 + j;
            af[j] = bf16b((k < 27) ? w1[k] : 0.f);
        }
        int ch0 = m0 + qq*4;
        float4 bias = *(const float4*)(eb1 + e*64 + ch0);

        // phase B: hidden = relu(conv1 + b1), one MFMA per 16ch x 16px.
        // Hidden pixels outside the image must be ZERO (reference conv2
        // zero-pads the H x W hidden map) -> mask.
        for (int nt = 0; nt < 21; ++nt) {
            int pix = nt*16 + mm;
            bool valid = pix < 324;
            int py = pix / 18, px = pix - py*18;
            int base = valid ? (py*20 + px) : 0;
            short8v bfr;
            #pragma unroll
            for (int j = 0; j < 8; ++j) bfr[j] = bf16b(in_s[base + offj[j]]);  // A=0 masks k>=27
            float4v d = __builtin_amdgcn_mfma_f32_16x16x32_bf16(af, bfr, (float4v){0.f,0.f,0.f,0.f}, 0, 0, 0);
            if (valid) {
                int gy = ty0 - 1 + py, gx = tx0 - 1 + px;
                float msk = (((unsigned)gy < 256u) && ((unsigned)gx < 256u)) ? 1.f : 0.f;
                float h0 = fmaxf(d[0] + bias.x, 0.f) * msk;
                float h1 = fmaxf(d[1] + bias.y, 0.f) * msk;
                float h2 = fmaxf(d[2] + bias.z, 0.f) * msk;
                float h3 = fmaxf(d[3] + bias.w, 0.f) * msk;
                union { _Float16 h[2]; unsigned u; } plo, phi;
                plo.h[0] = (_Float16)h0; plo.h[1] = (_Float16)h1;
                phi.h[0] = (_Float16)h2; phi.h[1] = (_Float16)h3;
                int c8 = ch0 >> 3, hf = (ch0 >> 2) & 1;
                hid[(c8*324 + pix)*2 + hf] = make_uint2(plo.u, phi.u);
            }
        }
        __syncthreads();

        // phase C: o[y,x] = sum_{c,tap} hid * w2, via b128 + dot2
        float oacc = 0.f;
        const uint4* hq = (const uint4*)hid;
        const uint4* wq = (const uint4*)w2s;
        #pragma unroll
        for (int kh = 0; kh < 3; ++kh) {
            #pragma unroll
            for (int kw = 0; kw < 3; ++kw) {
                int p = (oy + kh)*18 + ox + kw, tap = kh*3 + kw;
                #pragma unroll
                for (int c8 = 0; c8 < 8; ++c8) {
                    uint4 h = hq[c8*324 + p];
                    uint4 w = wq[c8*9 + tap];
                    oacc = dot2f(h.x, w.x, oacc);
                    oacc = dot2f(h.y, w.y, oacc);
                    oacc = dot2f(h.z, w.z, oacc);
                    oacc = dot2f(h.w, w.w, oacc);
                }
            }
        }
        accY += g * (oacc + eb2[e]);
    }
    out[(size_t)b*65536 + (ty0 + oy)*256 + tx0 + ox] = accY;
}

extern "C" void kernel_launch(void* const* d_in, const int* in_sizes, int n_in,
                              void* d_out, int out_size, void* d_ws, size_t ws_size,
                              hipStream_t stream) {
    (void)in_sizes; (void)n_in; (void)out_size; (void)ws_size;
    const float* x     = (const float*)d_in[0];
    const float* ref   = (const float*)d_in[1];
    const float* noise = (const float*)d_in[2];
    const float* mw1   = (const float*)d_in[3];
    const float* mb1   = (const float*)d_in[4];
    const float* mw2   = (const float*)d_in[5];
    const float* mb2   = (const float*)d_in[6];
    const float* enw   = (const float*)d_in[7];
    const float* enb   = (const float*)d_in[8];
    const float* fp    = (const float*)d_in[9];
    const float* wg    = (const float*)d_in[10];
    const float* wn    = (const float*)d_in[11];
    const float* ew1   = (const float*)d_in[12];
    const float* eb1   = (const float*)d_in[13];
    const float* ew2   = (const float*)d_in[14];
    const float* eb2   = (const float*)d_in[15];
    float* out = (float*)d_out;
    float* ws  = (float*)d_ws;

    hipMemsetAsync(d_ws, 0, 2048, stream);
    k_refsum  <<<dim3(48, 8),  256, 0, stream>>>(ref, ws);
    k_gatedots<<<dim3(48, 16), 256, 0, stream>>>(x, wg, wn, ws);
    k_gating  <<<1, 64, 0, stream>>>(noise, mw1, mb1, mw2, mb2, enw, enb, fp, ws, out);
    k_experts <<<4096, 256, 0, stream>>>(x, ew1, eb1, ew2, eb2, ws, out);
}

// Round 3
// 211.199 us; speedup vs baseline: 1.2196x; 1.2196x over previous
//
#include <hip/hip_runtime.h>
#include <hip/hip_bf16.h>
#include <math.h>

// ---------------- workspace layout (float indices) ----------------
#define WS_S    0      // s[b*3+c]            : 48
#define WS_G    64     // G[(b*3+c)*4+e]      : 192
#define WS_N    256    // N[(b*3+c)*4+e]      : 192
#define WS_GATE 448    // gates[b*4+e]        : 64

typedef float    float4v __attribute__((ext_vector_type(4)));
typedef short    short8v __attribute__((ext_vector_type(8)));
typedef _Float16 half8v  __attribute__((ext_vector_type(8)));

union Q4 { uint4 q; short8v s; half8v h; };

__device__ __forceinline__ unsigned short bf16b(float f) {
    unsigned u = __builtin_bit_cast(unsigned, f);
    u = (u + 0x7FFFu + ((u >> 16) & 1u)) >> 16;   // RNE
    return (unsigned short)u;
}

// ---------------- kernel A: s[b,c] = sum(ref[b,c,:,:]) ----------------
__global__ void k_refsum(const float* __restrict__ ref, float* __restrict__ ws) {
    int bc = blockIdx.x, chunk = blockIdx.y, t = threadIdx.x;
    const float4* p4 = (const float4*)(ref + (size_t)bc*65536 + (size_t)chunk*4096);
    float acc = 0.f;
    #pragma unroll
    for (int i = 0; i < 4; ++i) { float4 v = p4[i*256 + t]; acc += v.x + v.y + v.z + v.w; }
    #pragma unroll
    for (int off = 32; off > 0; off >>= 1) acc += __shfl_down(acc, off);
    __shared__ float red[4];
    if ((t & 63) == 0) red[t >> 6] = acc;
    __syncthreads();
    if (t == 0) atomicAdd(&ws[WS_S + bc], red[0] + red[1] + red[2] + red[3]);
}

// -------- kernel B: G[b,c,e] = sum_hw x*w_gate ; N likewise --------
__global__ void k_gatedots(const float* __restrict__ x, const float* __restrict__ wg,
                           const float* __restrict__ wn, float* __restrict__ ws) {
    int bc = blockIdx.x;                 // b*3+c
    int c  = bc % 3;
    int chunk = blockIdx.y, t = threadIdx.x;
    const float4* x4  = (const float4*)(x + (size_t)bc*65536 + (size_t)chunk*2048);
    const float4* wg4 = (const float4*)(wg + ((size_t)c*65536 + (size_t)chunk*2048)*4);
    const float4* wn4 = (const float4*)(wn + ((size_t)c*65536 + (size_t)chunk*2048)*4);
    float aG[4] = {0,0,0,0}, aN[4] = {0,0,0,0};
    #pragma unroll
    for (int i = 0; i < 2; ++i) {
        float4 xv = x4[i*256 + t];
        int row = (i*256 + t) * 4;
        float xs[4] = {xv.x, xv.y, xv.z, xv.w};
        #pragma unroll
        for (int l = 0; l < 4; ++l) {
            float4 g = wg4[row + l], n = wn4[row + l];
            aG[0] += xs[l]*g.x; aG[1] += xs[l]*g.y; aG[2] += xs[l]*g.z; aG[3] += xs[l]*g.w;
            aN[0] += xs[l]*n.x; aN[1] += xs[l]*n.y; aN[2] += xs[l]*n.z; aN[3] += xs[l]*n.w;
        }
    }
    #pragma unroll
    for (int off = 32; off > 0; off >>= 1) {
        #pragma unroll
        for (int e = 0; e < 4; ++e) { aG[e] += __shfl_down(aG[e], off); aN[e] += __shfl_down(aN[e], off); }
    }
    __shared__ float red[4][8];
    if ((t & 63) == 0) {
        #pragma unroll
        for (int e = 0; e < 4; ++e) { red[t>>6][e] = aG[e]; red[t>>6][4+e] = aN[e]; }
    }
    __syncthreads();
    if (t < 8) {
        float s = red[0][t] + red[1][t] + red[2][t] + red[3][t];
        if (t < 4) atomicAdd(&ws[WS_G + bc*4 + t],     s);
        else       atomicAdd(&ws[WS_N + bc*4 + (t-4)], s);
    }
}

// -------- kernel C: prompt, logits, top-k, gates, loss (tiny) --------
__global__ void k_gating(const float* __restrict__ noise,
                         const float* __restrict__ mw1, const float* __restrict__ mb1,
                         const float* __restrict__ mw2, const float* __restrict__ mb2,
                         const float* __restrict__ enw, const float* __restrict__ enb,
                         const float* __restrict__ fp,
                         float* __restrict__ ws, float* __restrict__ out) {
    __shared__ float gL[16][4], pL[16][4], cvs[2];
    int t = threadIdx.x;
    if (t < 16) {
        int b = t;
        float sc[3];
        for (int c = 0; c < 3; ++c) sc[c] = ws[WS_S + b*3 + c] * (1.f/256.f);
        float pooled[12];
        for (int i = 0; i < 12; ++i) { int r = i % 6; pooled[i] = (r < 3) ? sc[r] : 0.f; }
        float m1[6];
        for (int o = 0; o < 6; ++o) {
            float a = mb1[o];
            for (int i = 0; i < 12; ++i) a += mw1[o*12 + i] * pooled[i];
            m1[o] = fmaxf(a, 0.f);
        }
        float m2[6];
        for (int o = 0; o < 6; ++o) {
            float a = mb2[o];
            for (int i = 0; i < 6; ++i) a += mw2[o*6 + i] * m1[i];
            m2[o] = a * fp[(size_t)o * 33024];   // * fre_prompt[o,0,0]
        }
        float dc[3];
        for (int o = 0; o < 3; ++o) {            // only real-part channels matter
            float a = enb[o];
            for (int i = 0; i < 6; ++i) a += enw[o*6 + i] * m2[i];
            dc[o] = fmaxf(a, 0.f) * (1.f/256.f); // mean of irfft2 = Re(DC)/256
        }
        float mx = fmaxf(dc[0], fmaxf(dc[1], dc[2]));
        float e0 = expf(dc[0]-mx), e1 = expf(dc[1]-mx), e2 = expf(dc[2]-mx);
        float inv = 1.f / (e0 + e1 + e2);
        float pc[3] = { e0*inv + 1.f, e1*inv + 1.f, e2*inv + 1.f };
        float cl[4], sg[4], nz[4];
        for (int e = 0; e < 4; ++e) {
            float a = 0.f, nr = 0.f;
            for (int c = 0; c < 3; ++c) {
                a  += pc[c] * ws[WS_G + (b*3 + c)*4 + e];
                nr += pc[c] * ws[WS_N + (b*3 + c)*4 + e];
            }
            cl[e] = a;
            float sp = (nr > 20.f) ? nr : log1pf(expf(nr));
            sg[e] = sp + 0.01f;
            nz[e] = a + noise[b*4 + e] * sg[e];
        }
        int i0 = 0; float v0 = nz[0];
        for (int e = 1; e < 4; ++e) if (nz[e] > v0) { v0 = nz[e]; i0 = e; }
        int i1 = -1; float v1 = -3.4e38f;
        for (int e = 0; e < 4; ++e) if (e != i0 && nz[e] > v1) { v1 = nz[e]; i1 = e; }
        float v2 = -3.4e38f;
        for (int e = 0; e < 4; ++e) if (e != i0 && e != i1 && nz[e] > v2) v2 = nz[e];
        float ex = expf(v1 - v0), den = 1.f + ex;
        float gate[4] = {0.f, 0.f, 0.f, 0.f};
        gate[i0] = 1.f/den; gate[i1] = ex/den;
        for (int e = 0; e < 4; ++e) {
            ws[WS_GATE + b*4 + e] = gate[e];
            gL[b][e] = gate[e];
            float thr = (nz[e] > v2) ? v2 : v1;   // thr_in = 3rd-largest, thr_out = 2nd
            pL[b][e] = 0.5f * (1.f + erff((cl[e] - thr) / sg[e] * 0.70710678118f));
        }
    }
    __syncthreads();
    if (t < 2) {
        float v[4];
        for (int e = 0; e < 4; ++e) {
            float s = 0.f;
            for (int b = 0; b < 16; ++b) s += (t == 0) ? gL[b][e] : pL[b][e];
            v[e] = s;
        }
        float mean = 0.25f * (v[0] + v[1] + v[2] + v[3]);
        float var = 0.f;
        for (int e = 0; e < 4; ++e) { float d = v[e] - mean; var += d*d; }
        var *= (1.f/3.f);
        cvs[t] = var / (mean*mean + 1e-10f);
    }
    __syncthreads();
    if (t == 0) out[1048576] = (cvs[0] + cvs[1]) * 0.01f;
}

// -------- kernel D: fused expert convs, all-MFMA --------
// One 16x16 output tile per block. Phase B: conv1 via bf16 MFMA reading a
// pre-built swizzled im2col (built ONCE, expert-independent). Phase C:
// conv2 as two stages: stage1 f16 MFMA GEMM T[pix][tap] = hid . w2,
// stage2 = 9-tap LDS sum. LDS ~70 KB -> 2 blocks/CU.
__global__ __launch_bounds__(256, 2)
void k_experts(const float* __restrict__ x,  const float* __restrict__ ew1,
               const float* __restrict__ eb1, const float* __restrict__ ew2,
               const float* __restrict__ eb2, const float* __restrict__ ws,
               float* __restrict__ out) {
    __shared__ __align__(16) uint4 s_col[336*4];     // im2col bf16 [pix][32k], chunk-swizzled
    __shared__ __align__(16) uint4 s_hid[324*8];     // hidden f16 [pix][64c], chunk-swizzled
    __shared__ __align__(16) uint4 s_w2t[16*9];      // w2 f16 [tap][72c-stride]
    __shared__ __align__(16) _Float16 s_T[9*328];    // T[tap][324pix]

    int t = threadIdx.x;
    int b = blockIdx.x >> 8, tile = blockIdx.x & 255;
    int ty0 = (tile >> 4) * 16, tx0 = (tile & 15) * 16;
    const float* xb = x + (size_t)b * 196608;

    // ---- build im2col (once; direct from global, L1-cached overlaps) ----
    for (int p = t; p < 324; p += 256) {
        int py = p / 18, px = p - py*18;
        int gy0 = ty0 - 2 + py, gx0 = tx0 - 2 + px;
        unsigned short v[32];
        #pragma unroll
        for (int k = 0; k < 32; ++k) {
            float f = 0.f;
            if (k < 27) {
                int ci = k/9, r = k - ci*9, kh = r/3, kw = r - kh*3;
                int gy = gy0 + kh, gx = gx0 + kw;
                if ((unsigned)gy < 256u && (unsigned)gx < 256u)
                    f = xb[ci*65536 + gy*256 + gx];
            }
            v[k] = bf16b(f);
        }
        #pragma unroll
        for (int ch = 0; ch < 4; ++ch) {
            uint4 q;
            q.x = (unsigned)v[ch*8+0] | ((unsigned)v[ch*8+1] << 16);
            q.y = (unsigned)v[ch*8+2] | ((unsigned)v[ch*8+3] << 16);
            q.z = (unsigned)v[ch*8+4] | ((unsigned)v[ch*8+5] << 16);
            q.w = (unsigned)v[ch*8+6] | ((unsigned)v[ch*8+7] << 16);
            s_col[p*4 + ((ch + (p >> 1)) & 3)] = q;
        }
    }
    __syncthreads();

    int lane = t & 63, wv = t >> 6;
    int qq = lane >> 4, mm = lane & 15;
    int oy = t >> 4, ox = t & 15;
    float accY = 0.f;

    for (int e = 0; e < 4; ++e) {
        float g = ws[WS_GATE + b*4 + e];
        if (g == 0.f) continue;                 // block-uniform

        // stage w2 -> LDS as [tap][c] f16 (rows 9..15 garbage: cols unused)
        for (int i = t; i < 576; i += 256) {
            int c = i / 9, tap = i - c*9;
            ((_Float16*)s_w2t)[tap*72 + c] = (_Float16)ew2[e*576 + i];
        }

        // conv1 A-fragment: W[ch][k], ch = wv*16+mm, k = qq*8+j
        short8v af;
        const float* w1 = ew1 + e*1728 + (wv*16 + mm)*27;
        #pragma unroll
        for (int j = 0; j < 8; ++j) {
            int k = qq*8 + j;
            af[j] = (short)bf16b((k < 27) ? w1[k] : 0.f);
        }
        int ch0 = wv*16 + qq*4;
        float4 bias = *(const float4*)(eb1 + e*64 + ch0);
        int hchunk = ch0 >> 3, hsel = (ch0 >> 2) & 1;

        // ---- phase B: hidden = relu(conv1+b1), write f16 [pix][c] swizzled
        for (int nt = 0; nt < 21; ++nt) {
            int p = nt*16 + mm;
            Q4 bq; bq.q = s_col[p*4 + ((qq + (p >> 1)) & 3)];
            float4v d = __builtin_amdgcn_mfma_f32_16x16x32_bf16(
                af, bq.s, (float4v){0.f,0.f,0.f,0.f}, 0, 0, 0);
            if (p < 324) {
                int py = p / 18, px = p - py*18;
                int gy = ty0 - 1 + py, gx = tx0 - 1 + px;
                float msk = (((unsigned)gy < 256u) && ((unsigned)gx < 256u)) ? 1.f : 0.f;
                union { _Float16 h[4]; uint2 u; } pk;
                pk.h[0] = (_Float16)(fmaxf(d[0] + bias.x, 0.f) * msk);
                pk.h[1] = (_Float16)(fmaxf(d[1] + bias.y, 0.f) * msk);
                pk.h[2] = (_Float16)(fmaxf(d[2] + bias.z, 0.f) * msk);
                pk.h[3] = (_Float16)(fmaxf(d[3] + bias.w, 0.f) * msk);
                ((uint2*)&s_hid[p*8 + ((hchunk + p) & 7)])[hsel] = pk.u;
            }
        }
        __syncthreads();   // hid + w2t visible

        // ---- stage 1: T[pix][tap] = sum_c hid[pix][c] * w2[c][tap]
        // M=324 pix (21 groups), N=16 (9 taps used), K=64 (2 MFMA)
        Q4 bw0, bw1;
        bw0.q = s_w2t[mm*9 + qq];        // B[k=c][n=tap=mm], kstep 0
        bw1.q = s_w2t[mm*9 + 4 + qq];    // kstep 1
        for (int gi = wv; gi < 21; gi += 4) {
            int base = gi*16; if (base > 308) base = 308;   // overlap-recompute tail
            int p = base + mm;
            Q4 a0, a1;
            a0.q = s_hid[p*8 + ((qq + p) & 7)];
            a1.q = s_hid[p*8 + ((4 + qq + p) & 7)];
            float4v d = __builtin_amdgcn_mfma_f32_16x16x32_f16(
                a0.h, bw0.h, (float4v){0.f,0.f,0.f,0.f}, 0, 0, 0);
            d = __builtin_amdgcn_mfma_f32_16x16x32_f16(a1.h, bw1.h, d, 0, 0, 0);
            if (mm < 9) {   // col = tap = mm; rows = pixels base+qq*4+reg
                union { _Float16 h[4]; uint2 u; } pk;
                pk.h[0] = (_Float16)d[0]; pk.h[1] = (_Float16)d[1];
                pk.h[2] = (_Float16)d[2]; pk.h[3] = (_Float16)d[3];
                *(uint2*)&s_T[mm*328 + base + qq*4] = pk.u;
            }
        }
        __syncthreads();   // T visible

        // ---- stage 2: out = sum_tap T[(oy+kh)*18+ox+kw][tap]
        float oacc = 0.f;
        #pragma unroll
        for (int kh = 0; kh < 3; ++kh) {
            #pragma unroll
            for (int kw = 0; kw < 3; ++kw)
                oacc += (float)s_T[(kh*3 + kw)*328 + (oy + kh)*18 + ox + kw];
        }
        accY += g * (oacc + eb2[e]);
    }
    out[(size_t)b*65536 + (ty0 + oy)*256 + tx0 + ox] = accY;
}

extern "C" void kernel_launch(void* const* d_in, const int* in_sizes, int n_in,
                              void* d_out, int out_size, void* d_ws, size_t ws_size,
                              hipStream_t stream) {
    (void)in_sizes; (void)n_in; (void)out_size; (void)ws_size;
    const float* x     = (const float*)d_in[0];
    const float* ref   = (const float*)d_in[1];
    const float* noise = (const float*)d_in[2];
    const float* mw1   = (const float*)d_in[3];
    const float* mb1   = (const float*)d_in[4];
    const float* mw2   = (const float*)d_in[5];
    const float* mb2   = (const float*)d_in[6];
    const float* enw   = (const float*)d_in[7];
    const float* enb   = (const float*)d_in[8];
    const float* fp    = (const float*)d_in[9];
    const float* wg    = (const float*)d_in[10];
    const float* wn    = (const float*)d_in[11];
    const float* ew1   = (const float*)d_in[12];
    const float* eb1   = (const float*)d_in[13];
    const float* ew2   = (const float*)d_in[14];
    const float* eb2   = (const float*)d_in[15];
    float* out = (float*)d_out;
    float* ws  = (float*)d_ws;

    hipMemsetAsync(d_ws, 0, 2048, stream);
    k_refsum  <<<dim3(48, 16), 256, 0, stream>>>(ref, ws);
    k_gatedots<<<dim3(48, 32), 256, 0, stream>>>(x, wg, wn, ws);
    k_gating  <<<1, 64, 0, stream>>>(noise, mw1, mb1, mw2, mb2, enw, enb, fp, ws, out);
    k_experts <<<4096, 256, 0, stream>>>(x, ew1, eb1, ew2, eb2, ws, out);
}